// Round 8
// baseline (142.953 us; speedup 1.0000x reference)
//
#include <hip/hip_runtime.h>

#define NB 8      // NUM_BLOCK
#define NT 500    // NUM_FRAME
#define NF 257    // NUM_BIN
#define NC 8      // NUM_CH
#define NNUL 4    // NUM_NULL
#define LOWF 5
#define HIGHF 70
#define S_CHUNK 12
#define WARM 4
#define N_CHUNK 42   // ceil(NT / S_CHUNK)
#define AL 0.35f

__device__ __forceinline__ float dot4(const float4& a, const float4& b) {
    return a.x*b.x + a.y*b.y + a.z*b.z + a.w*b.w;
}
__device__ __forceinline__ float dot8(const float4& a0, const float4& a1,
                                      const float4& b0, const float4& b1) {
    return dot4(a0, b0) + dot4(a1, b1);
}
__device__ __forceinline__ float fast_rcp(float v) {
#if __has_builtin(__builtin_amdgcn_rcpf)
    return __builtin_amdgcn_rcpf(v);
#else
    return 1.0f / v;
#endif
}
__device__ __forceinline__ float fast_sqrt(float v) {
#if __has_builtin(__builtin_amdgcn_sqrtf)
    return __builtin_amdgcn_sqrtf(v);
#else
    return sqrtf(v);
#endif
}
__device__ __forceinline__ float clamp01(float v) {
#if __has_builtin(__builtin_amdgcn_fmed3f)
    return __builtin_amdgcn_fmed3f(v, 0.01f, 1.0f);   // v>=0 here: med3 == clip
#else
    return fminf(fmaxf(v, 0.01f), 1.0f);
#endif
}

// R8 = R7 RESUBMIT (R7 bench died at container level, no GPU data; source
// audited clean: LDS 50.9KB < 64KB static cap, all LDS/global offsets in
// bounds for S_CHUNK=12 incl. tail chunk k=41 nf=8; only delta vs passing
// R6 is 3 compile-time constants -> infra flake suspected).
// Theory (R7): warm-up tax = WARM/S_CHUNK. S=8: 6016 thread-frame units;
// S=12: 5344 (-11.2%). Grid 336 x 1024 (>1/CU + backfill). Probes
// work-vs-TLP: win -> push S=16; regress -> TLP-bound, pivot to stalls.
// R6 post-mortem context: inst diet gave 52.8->49.4us but ~30us is stall
// time insensitive to instruction count (latency-bound; HBM 16%).
// DO NOT raise launch_bounds 2nd arg: (1024,8) forced 32-VGPR budget on this
// ~60-VGPR body -> full spill (563MB writes, 306us) in R5.
// Kept: marching pointers, wave-15 extra path (f=256), fast rcp/sqrt/med3,
// quad-neighbor pw, predicated tr/ti stores, deferred-ratio epilogue
// (2 barriers/block), depth-1 prefetch (R3: quad loads via L1 beat shuffles).
__global__ __launch_bounds__(1024, 4) void dcf_fused_kernel(
    const float* __restrict__ x,           // (NB,NT,2,NF,NC) fp32
    const int* __restrict__ beam_id,       // (NB,)
    const float* __restrict__ targ_w,      // (8,2,NF,NC) fp32
    const float* __restrict__ null_w,      // (8,NNUL,2,NF,NC) fp32
    float* __restrict__ out)               // fp32: dcf (NB,NT,NF,NNUL) then targ (NB,NT,2,NF)
{
    const int tid = threadIdx.x;
    const int bid = blockIdx.x;
    const int b  = bid & 7;
    const int k  = bid >> 3;
    const int t0 = k * S_CHUNK;
    const int te = min(NT, t0 + S_CHUNK);
    int ts = t0 - WARM; if (ts < 0) ts = 0;

    const int f = tid >> 2;                // 0..255
    const int n = tid & 3;
    const int wid = tid >> 6;
    const int lane = tid & 63;
    const bool extra = (tid >= 1020);      // f=255 quad of wave 15 also does f=256

    __shared__ float s_w256[16 + 4 * 16];       // f=256 weights: twr,twi then per-n nwr,nwi
    __shared__ float s_part[S_CHUNK][25];       // per-frame ratio partials (waves 0..4 write)
    __shared__ float s_dcf[S_CHUNK][1028];      // pre-ratio dcf: [frame][tid], +4 for f=256

    const int beam = beam_id[b];
    const int pA = n & 1;                  // lane's "A" part: 0=real(even n), 1=imag(odd n)
    const int offA = pA * (NF * NC);
    const int offB = (1 - pA) * (NF * NC);
    const int psel = (n == 1 || n == 2) ? 1 : 0;   // targ part for this lane's partial
    const float nsign = pA ? -1.f : 1.f;

    // weights in registers: 6 float4 per thread
    float4 tw0, tw1, nwA0, nwA1, nwB0, nwB1;
    {
        const float* tp = targ_w + ((size_t)(beam * 2 + psel) * NF + f) * NC;
        tw0 = *(const float4*)(tp);  tw1 = *(const float4*)(tp + 4);
        const float* qp = null_w + ((size_t)((beam * NNUL + n) * 2) * NF + f) * NC;
        nwA0 = *(const float4*)(qp + offA);  nwA1 = *(const float4*)(qp + offA + 4);
        nwB0 = *(const float4*)(qp + offB);  nwB1 = *(const float4*)(qp + offB + 4);
    }
    if (tid < 16) {
        int p = tid >> 3, c = tid & 7;
        s_w256[tid] = targ_w[((size_t)(beam * 2 + p) * NF + 256) * NC + c];
    } else if (tid < 80) {
        int i = tid - 16;
        int nn = i >> 4, p = (i >> 3) & 1, c = i & 7;
        s_w256[tid] = null_w[((size_t)((beam * NNUL + nn) * 2 + p) * NF + 256) * NC + c];
    }
    __syncthreads();   // barrier 1 of 2 (weights visible)

    float phi_r = 0.f, phi_i = 0.f, psd = 0.f;
    float phi_r2 = 0.f, phi_i2 = 0.f, psd2 = 0.f;
    const float a = AL, oma = 1.0f - AL;
    const int rl = 2 * NF * NC;            // 4112 floats per (b,t)
    const bool in_red = (f >= LOWF) && (f < HIGHF);   // waves 0..4 only

    // marching pointers (A = lane's parity part, B = other)
    const float* xpa = x + (size_t)(b * NT + ts) * rl + f * NC + offA;
    const float* xpb = x + (size_t)(b * NT + ts) * rl + f * NC + offB;
    float4 pA0 = *(const float4*)(xpa);
    float4 pA1 = *(const float4*)(xpa + 4);
    float4 pB0 = *(const float4*)(xpb);
    float4 pB1 = *(const float4*)(xpb + 4);

    float* outT = out + (size_t)NB * NT * NF * NNUL;
    float* poT = outT + ((size_t)(b * NT + t0) * 2 + n) * NF + f;  // used when n<2
    float* sdp = &s_dcf[0][tid];
    float* spp = &s_part[0][wid * 5];

    for (int t = ts; t < te; ++t) {
        const float4 A0 = pA0, A1 = pA1, B0 = pB0, B1 = pB1;
        xpa += rl; xpb += rl;
        if (t + 1 < te) {
            pA0 = *(const float4*)(xpa);
            pA1 = *(const float4*)(xpa + 4);
            pB0 = *(const float4*)(xpb);
            pB1 = *(const float4*)(xpb + 4);
        }

        // targ dots via quad butterfly: lane n's partial d covers
        // n0: xr.twr  n1: xi.twi  n2: xr.twi  n3: xi.twr
        const float d = dot8(A0, A1, tw0, tw1);
        const float e = __shfl_xor(d, 1);
        const float u = (n < 2) ? ((n == 0) ? (d - e) : (e - d)) : (d + e);
        const float v = __shfl_xor(u, 2);
        const float tr = (n < 2) ? u : v;
        const float ti = (n < 2) ? v : u;

        // null dots (select-free via A/B address swap; nr needs one sign)
        const float P = dot8(A0, A1, nwA0, nwA1);
        const float Q = dot8(B0, B1, nwB0, nwB1);
        const float nr = nsign * (P - Q);
        const float ni = dot8(A0, A1, nwB0, nwB1) + dot8(B0, B1, nwA0, nwA1);

        // pw: |A|^2 here; quad-neighbor (n^1) holds |B|^2 in its sq
        float sq = dot4(A0, A0) + dot4(A1, A1);
        sq += __shfl_xor(sq, 1);
        const float pw = sq * 0.125f;

        if (t == 0) {  // exact asymmetric init from the reference
            phi_r = oma * tr * nr + ti * ni;
            phi_i = oma * ti * nr - tr * ni;
            psd   = oma * pw;
        } else {
            phi_r = a * phi_r + oma * (tr * nr + ti * ni);
            phi_i = a * phi_i + oma * (ti * nr - tr * ni);
            psd   = a * psd + oma * pw;
        }

        // f=256 on the f=255 quad of wave 15: weights from LDS,
        // x row = current frame's f=255 row + NC (pointers already advanced)
        float tr2 = 0.f, ti2 = 0.f;
        if (extra) {
            const float* xe  = xpa + (NC - rl);
            const float* xe2 = xpb + (NC - rl);
            const float4 eA0 = *(const float4*)(xe);
            const float4 eA1 = *(const float4*)(xe + 4);
            const float4 eB0 = *(const float4*)(xe2);
            const float4 eB1 = *(const float4*)(xe2 + 4);
            const float4 etw0 = *(const float4*)&s_w256[psel * 8];
            const float4 etw1 = *(const float4*)&s_w256[psel * 8 + 4];
            const float* nq = &s_w256[16 + n * 16];
            const float4 enA0 = *(const float4*)(nq + pA * 8);
            const float4 enA1 = *(const float4*)(nq + pA * 8 + 4);
            const float4 enB0 = *(const float4*)(nq + (1 - pA) * 8);
            const float4 enB1 = *(const float4*)(nq + (1 - pA) * 8 + 4);
            const float d2 = dot8(eA0, eA1, etw0, etw1);
            const float e2 = __shfl_xor(d2, 1);
            const float u2 = (n < 2) ? ((n == 0) ? (d2 - e2) : (e2 - d2)) : (d2 + e2);
            const float v2 = __shfl_xor(u2, 2);
            tr2 = (n < 2) ? u2 : v2;
            ti2 = (n < 2) ? v2 : u2;
            const float P2 = dot8(eA0, eA1, enA0, enA1);
            const float Q2 = dot8(eB0, eB1, enB0, enB1);
            const float nr2 = nsign * (P2 - Q2);
            const float ni2 = dot8(eA0, eA1, enB0, enB1) + dot8(eB0, eB1, enA0, enA1);
            float sq2 = dot4(eA0, eA0) + dot4(eA1, eA1);
            sq2 += __shfl_xor(sq2, 1);
            const float pw2 = sq2 * 0.125f;
            if (t == 0) {
                phi_r2 = oma * tr2 * nr2 + ti2 * ni2;
                phi_i2 = oma * ti2 * nr2 - tr2 * ni2;
                psd2   = oma * pw2;
            } else {
                phi_r2 = a * phi_r2 + oma * (tr2 * nr2 + ti2 * ni2);
                phi_i2 = a * phi_i2 + oma * (ti2 * nr2 - tr2 * ni2);
                psd2   = a * psd2 + oma * pw2;
            }
        }

        if (t >= t0) {
            const float phi = fast_sqrt(phi_r * phi_r + phi_i * phi_i);
            const float dcfv = clamp01(phi * fast_rcp(psd + 1e-13f));
            if (n < 2) *poT = (n == 0) ? tr : ti;
            *sdp = dcfv;                                 // pre-ratio, own slot
            if (extra) {
                const float phi2 = fast_sqrt(phi_r2 * phi_r2 + phi_i2 * phi_i2);
                const float dcf2v = clamp01(phi2 * fast_rcp(psd2 + 1e-13f));
                sdp[4] = dcf2v;                          // slot 1024+n (tid=1020+n)
                if (n < 2) poT[1] = (n == 0) ? tr2 : ti2;   // f=256 targ
            }
            // ratio partials: waves 0..4 hold f in [5,70); NO barrier here
            if (wid < 5) {
                float v_phi = in_red ? phi : 0.f;
                float v_psd = (in_red && n == 0) ? psd : 0.f;
                #pragma unroll
                for (int off = 4; off < 64; off <<= 1) {
                    v_phi += __shfl_xor(v_phi, off);
                    v_psd += __shfl_xor(v_psd, off);
                }
                if (lane < 4)  spp[lane] = v_phi;        // phi sum, n=lane
                if (lane == 0) spp[4]    = v_psd;        // psd sum
            }
            poT += 2 * NF; sdp += 1028; spp += 25;
        }
    }

    __syncthreads();   // barrier 2 of 2: all frames' s_dcf + s_part visible

    // uniform epilogue: apply ratio, write final dcf for all output frames
    float* po = out + ((size_t)(b * NT + t0) * NF + f) * NNUL + n;
    const float* sdr = &s_dcf[0][tid];
    const float* spr = &s_part[0][0];
    const int nf = te - t0;
    for (int fr = 0; fr < nf; ++fr) {
        const int t = t0 + fr;
        float dcfv = sdr[0];
        float dcf2v = extra ? sdr[4] : 0.f;
        if (t >= 1) {
            const float pre = spr[4] + spr[9] + spr[14] + spr[19] + spr[24];
            const float aft = spr[n] + spr[5 + n] + spr[10 + n] + spr[15 + n] + spr[20 + n];
            const float ratio = clamp01(aft * fast_rcp(pre + 1e-10f));
            dcfv = fast_sqrt(dcfv * ratio);
            if (extra) dcf2v = fast_sqrt(dcf2v * ratio);
        }
        *po = dcfv;
        if (extra) po[NNUL] = dcf2v;                     // f=256 slot
        po += NF * NNUL; sdr += 1028; spr += 25;
    }
}

extern "C" void kernel_launch(void* const* d_in, const int* in_sizes, int n_in,
                              void* d_out, int out_size, void* d_ws, size_t ws_size,
                              hipStream_t stream) {
    const float* x       = (const float*)d_in[0];
    const int*   beam_id = (const int*)d_in[1];
    const float* targ_w  = (const float*)d_in[2];
    const float* null_w  = (const float*)d_in[3];
    float* out           = (float*)d_out;
    (void)d_ws; (void)ws_size;

    dcf_fused_kernel<<<dim3(NB * N_CHUNK), dim3(1024), 0, stream>>>(
        x, beam_id, targ_w, null_w, out);
}

// Round 9
// 129.705 us; speedup vs baseline: 1.1021x; 1.1021x over previous
//
#include <hip/hip_runtime.h>

#define NB 8      // NUM_BLOCK
#define NT 500    // NUM_FRAME
#define NF 257    // NUM_BIN
#define NC 8      // NUM_CH
#define NNUL 4    // NUM_NULL
#define LOWF 5
#define HIGHF 70
#define S_CHUNK 8
#define WARM 4
#define N_CHUNK 63   // ceil(NT / S_CHUNK)
#define AL 0.35f

__device__ __forceinline__ float dot4(const float4& a, const float4& b) {
    return a.x*b.x + a.y*b.y + a.z*b.z + a.w*b.w;
}
__device__ __forceinline__ float dot8(const float4& a0, const float4& a1,
                                      const float4& b0, const float4& b1) {
    return dot4(a0, b0) + dot4(a1, b1);
}
__device__ __forceinline__ float fast_rcp(float v) {
#if __has_builtin(__builtin_amdgcn_rcpf)
    return __builtin_amdgcn_rcpf(v);
#else
    return 1.0f / v;
#endif
}
__device__ __forceinline__ float fast_sqrt(float v) {
#if __has_builtin(__builtin_amdgcn_sqrtf)
    return __builtin_amdgcn_sqrtf(v);
#else
    return sqrtf(v);
#endif
}
__device__ __forceinline__ float clamp01(float v) {
#if __has_builtin(__builtin_amdgcn_fmed3f)
    return __builtin_amdgcn_fmed3f(v, 0.01f, 1.0f);   // v>=0 here: med3 == clip
#else
    return fminf(fmaxf(v, 0.01f), 1.0f);
#endif
}

// R9: own-parity-only loads (VMEM halved), S_CHUNK back to 8.
// R8 post-mortem: S=12 shrank grid 504->336 < 512 block-slots (2x1024-thr
// blocks/CU wave-cap) -> occupancy 33->24%, 63us. Grid must stay ~>=500.
// R9 theory: per frame each thread issued 4 global_load_dwordx4, 4-way
// redundant within a quad (4KB L1 request traffic per wave-frame for 1KB
// unique) -> suspected L1/TA pipe saturation (VALUBusy 38% w/ full waves).
// Fix WITHOUT R3's float4-shuffle mistake: each lane loads ONLY its own
// parity plane (2 contiguous dwordx4); null dots restructured so each lane
// dots own data against FOUR weight vectors (own/neighbor null x own/other
// parity, held in regs from init):
//   P=A.W[n,p] X=A.W[n,1-p] s3=A.W[n^1,p] s4=A.W[n^1,1-p]
//   Q=shfl_xor(s3,1) Y=shfl_xor(s4,1)  (scalar DPP quad_perm, not float4)
//   nr=nsign*(P-Q) ni=X+Y   — products/order numerically identical to R6.
// VGPR-neutral: x live regs 32->16, null weights 16->32 (~60 total).
// DO NOT raise launch_bounds 2nd arg ((1024,8) => 32-VGPR budget => full
// spill, 563MB writes, 306us in R5). Keep grid 504 (S=8).
// Kept: marching pointers, wave-15 extra path (f=256), fast rcp/sqrt/med3,
// quad-neighbor pw, predicated tr/ti stores, deferred-ratio epilogue
// (2 barriers/block), depth-1 prefetch.
__global__ __launch_bounds__(1024, 4) void dcf_fused_kernel(
    const float* __restrict__ x,           // (NB,NT,2,NF,NC) fp32
    const int* __restrict__ beam_id,       // (NB,)
    const float* __restrict__ targ_w,      // (8,2,NF,NC) fp32
    const float* __restrict__ null_w,      // (8,NNUL,2,NF,NC) fp32
    float* __restrict__ out)               // fp32: dcf (NB,NT,NF,NNUL) then targ (NB,NT,2,NF)
{
    const int tid = threadIdx.x;
    const int bid = blockIdx.x;
    const int b  = bid & 7;
    const int k  = bid >> 3;
    const int t0 = k * S_CHUNK;
    const int te = min(NT, t0 + S_CHUNK);
    int ts = t0 - WARM; if (ts < 0) ts = 0;

    const int f = tid >> 2;                // 0..255
    const int n = tid & 3;
    const int wid = tid >> 6;
    const int lane = tid & 63;
    const bool extra = (tid >= 1020);      // f=255 quad of wave 15 also does f=256

    __shared__ float s_w256[16 + 4 * 16];       // f=256 weights: twr,twi then per-n nwr,nwi
    __shared__ float s_part[S_CHUNK][25];       // per-frame ratio partials (waves 0..4 write)
    __shared__ float s_dcf[S_CHUNK][1028];      // pre-ratio dcf: [frame][tid], +4 for f=256

    const int beam = beam_id[b];
    const int pA = n & 1;                  // lane's parity: 0=real(even n), 1=imag(odd n)
    const int offA = pA * (NF * NC);       // own-parity plane offset
    const int offB = (1 - pA) * (NF * NC); // other-parity plane offset (weights only)
    const int psel = (n == 1 || n == 2) ? 1 : 0;   // targ part for this lane's partial
    const float nsign = pA ? -1.f : 1.f;

    // weights in registers: 10 float4 per thread (targ + 4 null vectors)
    float4 tw0, tw1, w10, w11, w20, w21, w30, w31, w40, w41;
    {
        const float* tp = targ_w + ((size_t)(beam * 2 + psel) * NF + f) * NC;
        tw0 = *(const float4*)(tp);  tw1 = *(const float4*)(tp + 4);
        const float* qp  = null_w + ((size_t)((beam * NNUL + n) * 2) * NF + f) * NC;
        const float* qpx = null_w + ((size_t)((beam * NNUL + (n ^ 1)) * 2) * NF + f) * NC;
        w10 = *(const float4*)(qp  + offA);  w11 = *(const float4*)(qp  + offA + 4);
        w20 = *(const float4*)(qp  + offB);  w21 = *(const float4*)(qp  + offB + 4);
        w30 = *(const float4*)(qpx + offA);  w31 = *(const float4*)(qpx + offA + 4);
        w40 = *(const float4*)(qpx + offB);  w41 = *(const float4*)(qpx + offB + 4);
    }
    if (tid < 16) {
        int p = tid >> 3, c = tid & 7;
        s_w256[tid] = targ_w[((size_t)(beam * 2 + p) * NF + 256) * NC + c];
    } else if (tid < 80) {
        int i = tid - 16;
        int nn = i >> 4, p = (i >> 3) & 1, c = i & 7;
        s_w256[tid] = null_w[((size_t)((beam * NNUL + nn) * 2 + p) * NF + 256) * NC + c];
    }
    __syncthreads();   // barrier 1 of 2 (weights visible)

    float phi_r = 0.f, phi_i = 0.f, psd = 0.f;
    float phi_r2 = 0.f, phi_i2 = 0.f, psd2 = 0.f;
    const float a = AL, oma = 1.0f - AL;
    const int rl = 2 * NF * NC;            // 4112 floats per (b,t)
    const bool in_red = (f >= LOWF) && (f < HIGHF);   // waves 0..4 only

    // marching pointer: own parity plane only (2 contiguous dwordx4/frame)
    const float* xpa = x + (size_t)(b * NT + ts) * rl + f * NC + offA;
    float4 pA0 = *(const float4*)(xpa);
    float4 pA1 = *(const float4*)(xpa + 4);

    float* outT = out + (size_t)NB * NT * NF * NNUL;
    float* poT = outT + ((size_t)(b * NT + t0) * 2 + n) * NF + f;  // used when n<2
    float* sdp = &s_dcf[0][tid];
    float* spp = &s_part[0][wid * 5];

    for (int t = ts; t < te; ++t) {
        const float4 A0 = pA0, A1 = pA1;
        xpa += rl;
        if (t + 1 < te) {
            pA0 = *(const float4*)(xpa);
            pA1 = *(const float4*)(xpa + 4);
        }

        // targ dots via quad butterfly (own parity only — unchanged):
        // n0: xr.twr  n1: xi.twi  n2: xr.twi  n3: xi.twr
        const float d = dot8(A0, A1, tw0, tw1);
        const float e = __shfl_xor(d, 1);
        const float u = (n < 2) ? ((n == 0) ? (d - e) : (e - d)) : (d + e);
        const float v = __shfl_xor(u, 2);
        const float tr = (n < 2) ? u : v;
        const float ti = (n < 2) ? v : u;

        // null dots: own-data x 4 weight sets, scalar quad exchange
        const float P  = dot8(A0, A1, w10, w11);   // A.W[n,p]
        const float X  = dot8(A0, A1, w20, w21);   // A.W[n,1-p]
        const float s3 = dot8(A0, A1, w30, w31);   // A.W[n^1,p]   -> neighbor's Q
        const float s4 = dot8(A0, A1, w40, w41);   // A.W[n^1,1-p] -> neighbor's Y
        const float Q  = __shfl_xor(s3, 1);
        const float Y  = __shfl_xor(s4, 1);
        const float nr = nsign * (P - Q);
        const float ni = X + Y;

        // pw: |A|^2 here; quad-neighbor (n^1) holds the other parity
        float sq = dot4(A0, A0) + dot4(A1, A1);
        sq += __shfl_xor(sq, 1);
        const float pw = sq * 0.125f;

        if (t == 0) {  // exact asymmetric init from the reference
            phi_r = oma * tr * nr + ti * ni;
            phi_i = oma * ti * nr - tr * ni;
            psd   = oma * pw;
        } else {
            phi_r = a * phi_r + oma * (tr * nr + ti * ni);
            phi_i = a * phi_i + oma * (ti * nr - tr * ni);
            psd   = a * psd + oma * pw;
        }

        // f=256 on the f=255 quad of wave 15: weights from LDS,
        // x row = current frame's f=255 row + NC (pointer already advanced)
        float tr2 = 0.f, ti2 = 0.f;
        if (extra) {
            const float* xe = xpa + (NC - rl);     // frame t, f=256, own parity
            const float4 eA0 = *(const float4*)(xe);
            const float4 eA1 = *(const float4*)(xe + 4);
            const float4 etw0 = *(const float4*)&s_w256[psel * 8];
            const float4 etw1 = *(const float4*)&s_w256[psel * 8 + 4];
            const float* nq  = &s_w256[16 + n * 16];
            const float* nqx = &s_w256[16 + (n ^ 1) * 16];
            const float4 e10 = *(const float4*)(nq  + pA * 8);
            const float4 e11 = *(const float4*)(nq  + pA * 8 + 4);
            const float4 e20 = *(const float4*)(nq  + (1 - pA) * 8);
            const float4 e21 = *(const float4*)(nq  + (1 - pA) * 8 + 4);
            const float4 e30 = *(const float4*)(nqx + pA * 8);
            const float4 e31 = *(const float4*)(nqx + pA * 8 + 4);
            const float4 e40 = *(const float4*)(nqx + (1 - pA) * 8);
            const float4 e41 = *(const float4*)(nqx + (1 - pA) * 8 + 4);
            const float d2 = dot8(eA0, eA1, etw0, etw1);
            const float e2 = __shfl_xor(d2, 1);
            const float u2 = (n < 2) ? ((n == 0) ? (d2 - e2) : (e2 - d2)) : (d2 + e2);
            const float v2 = __shfl_xor(u2, 2);
            tr2 = (n < 2) ? u2 : v2;
            ti2 = (n < 2) ? v2 : u2;
            const float P2  = dot8(eA0, eA1, e10, e11);
            const float X2  = dot8(eA0, eA1, e20, e21);
            const float s32 = dot8(eA0, eA1, e30, e31);
            const float s42 = dot8(eA0, eA1, e40, e41);
            const float Q2  = __shfl_xor(s32, 1);
            const float Y2  = __shfl_xor(s42, 1);
            const float nr2 = nsign * (P2 - Q2);
            const float ni2 = X2 + Y2;
            float sq2 = dot4(eA0, eA0) + dot4(eA1, eA1);
            sq2 += __shfl_xor(sq2, 1);
            const float pw2 = sq2 * 0.125f;
            if (t == 0) {
                phi_r2 = oma * tr2 * nr2 + ti2 * ni2;
                phi_i2 = oma * ti2 * nr2 - tr2 * ni2;
                psd2   = oma * pw2;
            } else {
                phi_r2 = a * phi_r2 + oma * (tr2 * nr2 + ti2 * ni2);
                phi_i2 = a * phi_i2 + oma * (ti2 * nr2 - tr2 * ni2);
                psd2   = a * psd2 + oma * pw2;
            }
        }

        if (t >= t0) {
            const float phi = fast_sqrt(phi_r * phi_r + phi_i * phi_i);
            const float dcfv = clamp01(phi * fast_rcp(psd + 1e-13f));
            if (n < 2) *poT = (n == 0) ? tr : ti;
            *sdp = dcfv;                                 // pre-ratio, own slot
            if (extra) {
                const float phi2 = fast_sqrt(phi_r2 * phi_r2 + phi_i2 * phi_i2);
                const float dcf2v = clamp01(phi2 * fast_rcp(psd2 + 1e-13f));
                sdp[4] = dcf2v;                          // slot 1024+n (tid=1020+n)
                if (n < 2) poT[1] = (n == 0) ? tr2 : ti2;   // f=256 targ
            }
            // ratio partials: waves 0..4 hold f in [5,70); NO barrier here
            if (wid < 5) {
                float v_phi = in_red ? phi : 0.f;
                float v_psd = (in_red && n == 0) ? psd : 0.f;
                #pragma unroll
                for (int off = 4; off < 64; off <<= 1) {
                    v_phi += __shfl_xor(v_phi, off);
                    v_psd += __shfl_xor(v_psd, off);
                }
                if (lane < 4)  spp[lane] = v_phi;        // phi sum, n=lane
                if (lane == 0) spp[4]    = v_psd;        // psd sum
            }
            poT += 2 * NF; sdp += 1028; spp += 25;
        }
    }

    __syncthreads();   // barrier 2 of 2: all frames' s_dcf + s_part visible

    // uniform epilogue: apply ratio, write final dcf for all output frames
    float* po = out + ((size_t)(b * NT + t0) * NF + f) * NNUL + n;
    const float* sdr = &s_dcf[0][tid];
    const float* spr = &s_part[0][0];
    const int nf = te - t0;
    for (int fr = 0; fr < nf; ++fr) {
        const int t = t0 + fr;
        float dcfv = sdr[0];
        float dcf2v = extra ? sdr[4] : 0.f;
        if (t >= 1) {
            const float pre = spr[4] + spr[9] + spr[14] + spr[19] + spr[24];
            const float aft = spr[n] + spr[5 + n] + spr[10 + n] + spr[15 + n] + spr[20 + n];
            const float ratio = clamp01(aft * fast_rcp(pre + 1e-10f));
            dcfv = fast_sqrt(dcfv * ratio);
            if (extra) dcf2v = fast_sqrt(dcf2v * ratio);
        }
        *po = dcfv;
        if (extra) po[NNUL] = dcf2v;                     // f=256 slot
        po += NF * NNUL; sdr += 1028; spr += 25;
    }
}

extern "C" void kernel_launch(void* const* d_in, const int* in_sizes, int n_in,
                              void* d_out, int out_size, void* d_ws, size_t ws_size,
                              hipStream_t stream) {
    const float* x       = (const float*)d_in[0];
    const int*   beam_id = (const int*)d_in[1];
    const float* targ_w  = (const float*)d_in[2];
    const float* null_w  = (const float*)d_in[3];
    float* out           = (float*)d_out;
    (void)d_ws; (void)ws_size;

    dcf_fused_kernel<<<dim3(NB * N_CHUNK), dim3(1024), 0, stream>>>(
        x, beam_id, targ_w, null_w, out);
}